// Round 3
// baseline (341.952 us; speedup 1.0000x reference)
//
#include <hip/hip_runtime.h>
#include <hip/hip_bf16.h>

#define N_NODES 100000
#define N_EDGES 1600000
#define IN_F 256
#define OUT_F 128

typedef __attribute__((ext_vector_type(8))) __bf16 bf16x8;
typedef __attribute__((ext_vector_type(4))) float f32x4;

// ---------- helpers ----------
__device__ __forceinline__ float bf16_lo(unsigned int p) {
    union { unsigned int i; float f; } u; u.i = p << 16; return u.f;
}
__device__ __forceinline__ float bf16_hi(unsigned int p) {
    union { unsigned int i; float f; } u; u.i = p & 0xffff0000u; return u.f;
}
__device__ __forceinline__ unsigned short f2bf(float f) {
    union { float f; unsigned int i; } u; u.f = f;
    unsigned int r = u.i + 0x7fff + ((u.i >> 16) & 1);   // RNE (finite data only)
    return (unsigned short)(r >> 16);
}

// ---------- kernel 0: W fp32 [K][N] -> bf16 transposed wt [N][K] ----------
__global__ __launch_bounds__(256) void wconv_kernel(
    const float* __restrict__ weight, unsigned short* __restrict__ wt) {
  int id = blockIdx.x * 256 + threadIdx.x;   // 32768 = 256*128
  int col = id & 127;
  int k   = id >> 7;
  wt[(size_t)col * IN_F + k] = f2bf(weight[(size_t)k * OUT_F + col]);
}

// ---------- kernel 1: support = X @ W via MFMA, bf16 output ----------
// block = 256 thr (4 waves). Tile: 64 rows x 128 cols, K_STEP=64 (4 steps).
#define XS 72
#define WSS 72
__global__ __launch_bounds__(256) void gemm_xw_mfma(
    const float* __restrict__ x, const unsigned short* __restrict__ wt,
    unsigned int* __restrict__ support /* N_NODES x 64 uints (2 bf16 each) */) {
  __shared__ unsigned short smem[13824];
  unsigned short* Xt = smem;           // [64][XS]
  unsigned short* Wt = smem + 4608;    // [128][WSS]

  const int tid  = threadIdx.x;
  const int w    = tid >> 6;
  const int lane = tid & 63;
  const int l15  = lane & 15;
  const int lhi  = lane >> 4;
  const int row0 = blockIdx.x * 64;

  f32x4 acc[8];
  #pragma unroll
  for (int nt = 0; nt < 8; ++nt) acc[nt] = (f32x4){0.f, 0.f, 0.f, 0.f};

  for (int ks = 0; ks < 4; ++ks) {
    // stage X tile: 64 rows x 64 k fp32 -> bf16 LDS
    {
      int r = tid >> 2;
      int srow = row0 + r; if (srow >= N_NODES) srow = N_NODES - 1;
      const float* xp = x + (size_t)srow * IN_F + ks * 64;
      #pragma unroll
      for (int i = 0; i < 4; ++i) {
        int f4 = (tid & 3) + i * 4;          // 0..15
        float4 v = *(const float4*)(xp + f4 * 4);
        ushort4 h;
        h.x = f2bf(v.x); h.y = f2bf(v.y); h.z = f2bf(v.z); h.w = f2bf(v.w);
        *(ushort4*)(&Xt[r * XS + f4 * 4]) = h;
      }
    }
    // stage W tile: 128 cols x 64 k bf16 (already transposed in global)
    {
      int c = tid >> 1;
      const unsigned short* wp = wt + (size_t)c * IN_F + ks * 64;
      #pragma unroll
      for (int i = 0; i < 4; ++i) {
        int c8 = (tid & 1) * 4 + i;          // 0..7, 8 bf16 each
        uint4 v = *(const uint4*)(wp + c8 * 8);
        *(uint4*)(&Wt[c * WSS + c8 * 8]) = v;
      }
    }
    __syncthreads();
    #pragma unroll
    for (int kt = 0; kt < 2; ++kt) {
      bf16x8 a = *(const bf16x8*)(&Xt[(w * 16 + l15) * XS + kt * 32 + lhi * 8]);
      #pragma unroll
      for (int nt = 0; nt < 8; ++nt) {
        bf16x8 b = *(const bf16x8*)(&Wt[(nt * 16 + l15) * WSS + kt * 32 + lhi * 8]);
        acc[nt] = __builtin_amdgcn_mfma_f32_16x16x32_bf16(a, b, acc[nt], 0, 0, 0);
      }
    }
    __syncthreads();
  }

  // epilogue: acc -> LDS bf16 [64][128] -> coalesced global store
  unsigned short* Ot = smem;   // reuse
  #pragma unroll
  for (int nt = 0; nt < 8; ++nt)
    #pragma unroll
    for (int r = 0; r < 4; ++r) {
      int orow = w * 16 + lhi * 4 + r;       // D row = (lane>>4)*4 + reg
      int ocol = nt * 16 + l15;              // D col = lane&15
      Ot[orow * 128 + ocol] = f2bf(acc[nt][r]);
    }
  __syncthreads();
  {
    int r = tid >> 2;
    int grow = row0 + r;
    if (grow < N_NODES) {
      const uint4* src = (const uint4*)(&Ot[r * 128]);
      uint4* dst = (uint4*)(support + (size_t)grow * 64);
      int c = tid & 3;
      #pragma unroll
      for (int i = 0; i < 4; ++i) dst[c + i * 4] = src[c + i * 4];
    }
  }
}

// ---------- kernel 2: row_ptr via binary search (edge_row is sorted) ----------
__global__ __launch_bounds__(256) void rowptr_kernel(
    const int* __restrict__ edge_row, int* __restrict__ row_ptr) {
  int r = blockIdx.x * 256 + threadIdx.x;
  if (r > N_NODES) return;
  int lo = 0, hi = N_EDGES;
  while (lo < hi) {
    int mid = (lo + hi) >> 1;
    if (edge_row[mid] < r) lo = mid + 1; else hi = mid;
  }
  row_ptr[r] = lo;  // first edge with row >= r
}

// ---------- kernel 3: CSR SpMM, one wave per row, 2 edges/gather, 8 gathers in flight ----------
__global__ __launch_bounds__(256) void spmm_kernel(
    const unsigned int* __restrict__ support,  // 64 uints / row (2 bf16 each)
    const int* __restrict__ row_ptr,
    const int* __restrict__ edge_col,
    const float* __restrict__ edge_val,
    const float* __restrict__ bias,
    float* __restrict__ out) {
  int wid = (blockIdx.x * 256 + threadIdx.x) >> 6;   // row id (wave-uniform)
  wid = __builtin_amdgcn_readfirstlane(wid);
  if (wid >= N_NODES) return;
  const int  lane    = threadIdx.x & 63;
  const int  l32     = lane & 31;
  const bool hi_half = (lane >= 32);

  int e   = row_ptr[wid];
  int end = row_ptr[wid + 1];

  float4 acc = make_float4(0.f, 0.f, 0.f, 0.f);

  while (e < end) {
    if (e + 16 <= N_EDGES) {
      // 16 edges, predicated on `end`; dead edges clamp to last live edge (L1 hit, val=0)
      int c[16]; float v[16];
      #pragma unroll
      for (int i = 0; i < 16; ++i) {
        int  idx  = e + i < end ? e + i : end - 1;   // uniform scalar select
        c[i] = edge_col[idx];
        v[i] = e + i < end ? edge_val[idx] : 0.f;
      }
      uint2 sv[8];
      #pragma unroll
      for (int i = 0; i < 8; ++i) {
        int col = hi_half ? c[2 * i + 1] : c[2 * i];
        sv[i] = *(const uint2*)(support + (size_t)col * 64 + l32 * 2);
      }
      #pragma unroll
      for (int i = 0; i < 8; ++i) {
        float val = hi_half ? v[2 * i + 1] : v[2 * i];
        acc.x += val * bf16_lo(sv[i].x);
        acc.y += val * bf16_hi(sv[i].x);
        acc.z += val * bf16_lo(sv[i].y);
        acc.w += val * bf16_hi(sv[i].y);
      }
      e += 16;
    } else {
      // safe tail near the end of the edge arrays
      for (; e < end; e += 2) {
        int   c0 = edge_col[e];
        int   i1 = (e + 1 < end) ? e + 1 : e;
        int   c1 = edge_col[i1];
        float v0 = edge_val[e];
        float v1 = (e + 1 < end) ? edge_val[i1] : 0.f;
        int col = hi_half ? c1 : c0;
        uint2 s = *(const uint2*)(support + (size_t)col * 64 + l32 * 2);
        float val = hi_half ? v1 : v0;
        acc.x += val * bf16_lo(s.x);
        acc.y += val * bf16_hi(s.x);
        acc.z += val * bf16_lo(s.y);
        acc.w += val * bf16_hi(s.y);
      }
    }
  }

  // combine the two half-wave partial sums
  acc.x += __shfl_xor(acc.x, 32, 64);
  acc.y += __shfl_xor(acc.y, 32, 64);
  acc.z += __shfl_xor(acc.z, 32, 64);
  acc.w += __shfl_xor(acc.w, 32, 64);

  if (!hi_half) {
    float4 b = *(const float4*)(bias + l32 * 4);
    float4 o;
    o.x = acc.x + b.x; o.y = acc.y + b.y;
    o.z = acc.z + b.z; o.w = acc.w + b.w;
    *(float4*)(out + (size_t)wid * OUT_F + l32 * 4) = o;
  }
}

// ---------- launch ----------
extern "C" void kernel_launch(void* const* d_in, const int* in_sizes, int n_in,
                              void* d_out, int out_size, void* d_ws, size_t ws_size,
                              hipStream_t stream) {
  const float* x        = (const float*)d_in[0];
  const int*   edge_row = (const int*)  d_in[1];
  const int*   edge_col = (const int*)  d_in[2];
  const float* edge_val = (const float*)d_in[3];
  const float* weight   = (const float*)d_in[4];
  const float* bias     = (const float*)d_in[5];
  float* out = (float*)d_out;

  unsigned char* ws = (unsigned char*)d_ws;
  size_t support_bytes = (size_t)N_NODES * OUT_F * 2;            // 25.6 MB bf16
  unsigned int* support = (unsigned int*)ws;
  size_t rp_off = (support_bytes + 255) & ~(size_t)255;
  int* row_ptr = (int*)(ws + rp_off);
  size_t wt_off = (rp_off + (size_t)(N_NODES + 1) * 4 + 255) & ~(size_t)255;
  unsigned short* wt = (unsigned short*)(ws + wt_off);

  hipLaunchKernelGGL(rowptr_kernel, dim3((N_NODES + 1 + 255) / 256), dim3(256), 0, stream,
                     edge_row, row_ptr);
  hipLaunchKernelGGL(wconv_kernel, dim3(128), dim3(256), 0, stream,
                     weight, wt);
  hipLaunchKernelGGL(gemm_xw_mfma, dim3((N_NODES + 63) / 64), dim3(256), 0, stream,
                     x, wt, support);
  hipLaunchKernelGGL(spmm_kernel, dim3(N_NODES / 4), dim3(256), 0, stream,
                     support, row_ptr, edge_col, edge_val, bias, out);
}

// Round 4
// 104.235 us; speedup vs baseline: 3.2806x; 3.2806x over previous
//
#include <hip/hip_runtime.h>
#include <hip/hip_bf16.h>

#define N_NODES 100000
#define N_EDGES 1600000
#define IN_F 256
#define OUT_F 128

typedef __attribute__((ext_vector_type(8))) __bf16 bf16x8;
typedef __attribute__((ext_vector_type(4))) float f32x4;

// ---------- helpers ----------
__device__ __forceinline__ float bf16_lo(unsigned int p) {
    union { unsigned int i; float f; } u; u.i = p << 16; return u.f;
}
__device__ __forceinline__ float bf16_hi(unsigned int p) {
    union { unsigned int i; float f; } u; u.i = p & 0xffff0000u; return u.f;
}
__device__ __forceinline__ unsigned short f2bf(float f) {
    union { float f; unsigned int i; } u; u.f = f;
    unsigned int r = u.i + 0x7fff + ((u.i >> 16) & 1);   // RNE (finite data only)
    return (unsigned short)(r >> 16);
}

// ---------- kernel 0: W fp32 [K][N] -> bf16 transposed wt [N][K] ----------
__global__ __launch_bounds__(256) void wconv_kernel(
    const float* __restrict__ weight, unsigned short* __restrict__ wt) {
  int id = blockIdx.x * 256 + threadIdx.x;   // 32768 = 256*128
  int col = id & 127;
  int k   = id >> 7;
  wt[(size_t)col * IN_F + k] = f2bf(weight[(size_t)k * OUT_F + col]);
}

// ---------- kernel 1: support = X @ W via MFMA, bf16 output ----------
#define XS 72
#define WSS 72
__global__ __launch_bounds__(256) void gemm_xw_mfma(
    const float* __restrict__ x, const unsigned short* __restrict__ wt,
    unsigned int* __restrict__ support /* N_NODES x 64 uints (2 bf16 each) */) {
  __shared__ unsigned short smem[13824];
  unsigned short* Xt = smem;           // [64][XS]
  unsigned short* Wt = smem + 4608;    // [128][WSS]

  const int tid  = threadIdx.x;
  const int w    = tid >> 6;
  const int lane = tid & 63;
  const int l15  = lane & 15;
  const int lhi  = lane >> 4;
  const int row0 = blockIdx.x * 64;

  f32x4 acc[8];
  #pragma unroll
  for (int nt = 0; nt < 8; ++nt) acc[nt] = (f32x4){0.f, 0.f, 0.f, 0.f};

  for (int ks = 0; ks < 4; ++ks) {
    {
      int r = tid >> 2;
      int srow = row0 + r; if (srow >= N_NODES) srow = N_NODES - 1;
      const float* xp = x + (size_t)srow * IN_F + ks * 64;
      #pragma unroll
      for (int i = 0; i < 4; ++i) {
        int f4 = (tid & 3) + i * 4;          // 0..15
        float4 v = *(const float4*)(xp + f4 * 4);
        ushort4 h;
        h.x = f2bf(v.x); h.y = f2bf(v.y); h.z = f2bf(v.z); h.w = f2bf(v.w);
        *(ushort4*)(&Xt[r * XS + f4 * 4]) = h;
      }
    }
    {
      int c = tid >> 1;
      const unsigned short* wp = wt + (size_t)c * IN_F + ks * 64;
      #pragma unroll
      for (int i = 0; i < 4; ++i) {
        int c8 = (tid & 1) * 4 + i;          // 0..7, 8 bf16 each
        uint4 v = *(const uint4*)(wp + c8 * 8);
        *(uint4*)(&Wt[c * WSS + c8 * 8]) = v;
      }
    }
    __syncthreads();
    #pragma unroll
    for (int kt = 0; kt < 2; ++kt) {
      bf16x8 a = *(const bf16x8*)(&Xt[(w * 16 + l15) * XS + kt * 32 + lhi * 8]);
      #pragma unroll
      for (int nt = 0; nt < 8; ++nt) {
        bf16x8 b = *(const bf16x8*)(&Wt[(nt * 16 + l15) * WSS + kt * 32 + lhi * 8]);
        acc[nt] = __builtin_amdgcn_mfma_f32_16x16x32_bf16(a, b, acc[nt], 0, 0, 0);
      }
    }
    __syncthreads();
  }

  // epilogue: acc -> LDS bf16 [64][128] -> coalesced global store
  unsigned short* Ot = smem;   // reuse
  #pragma unroll
  for (int nt = 0; nt < 8; ++nt)
    #pragma unroll
    for (int r = 0; r < 4; ++r) {
      int orow = w * 16 + lhi * 4 + r;       // D row = (lane>>4)*4 + reg
      int ocol = nt * 16 + l15;              // D col = lane&15
      Ot[orow * 128 + ocol] = f2bf(acc[nt][r]);
    }
  __syncthreads();
  {
    int r = tid >> 2;
    int grow = row0 + r;
    if (grow < N_NODES) {
      const uint4* src = (const uint4*)(&Ot[r * 128]);
      uint4* dst = (uint4*)(support + (size_t)grow * 64);
      int c = tid & 3;
      #pragma unroll
      for (int i = 0; i < 4; ++i) dst[c + i * 4] = src[c + i * 4];
    }
  }
}

// ---------- kernel 2: row_ptr via binary search (edge_row is sorted) ----------
__global__ __launch_bounds__(256) void rowptr_kernel(
    const int* __restrict__ edge_row, int* __restrict__ row_ptr) {
  int r = blockIdx.x * 256 + threadIdx.x;
  if (r > N_NODES) return;
  int lo = 0, hi = N_EDGES;
  while (lo < hi) {
    int mid = (lo + hi) >> 1;
    if (edge_row[mid] < r) lo = mid + 1; else hi = mid;
  }
  row_ptr[r] = lo;  // first edge with row >= r
}

// ---------- kernel 3: CSR SpMM — 16 edges/chunk, named scalars only ----------
// wid is wave-uniform (readfirstlane) -> edge col/val loads become s_loads.
// 8 independent uint2 gathers in flight per chunk (2 edges per gather).
__global__ __launch_bounds__(256) void spmm_kernel(
    const unsigned int* __restrict__ support,  // 64 uints / row (2 bf16 each)
    const int* __restrict__ row_ptr,
    const int* __restrict__ edge_col,
    const float* __restrict__ edge_val,
    const float* __restrict__ bias,
    float* __restrict__ out) {
  int wid = (blockIdx.x * 256 + threadIdx.x) >> 6;   // row id (wave-uniform)
  wid = __builtin_amdgcn_readfirstlane(wid);
  if (wid >= N_NODES) return;
  const int  lane    = threadIdx.x & 63;
  const int  l32     = lane & 31;
  const bool hi_half = (lane >= 32);

  int e   = row_ptr[wid];
  int end = row_ptr[wid + 1];

  float4 acc = make_float4(0.f, 0.f, 0.f, 0.f);

  while (e < end) {
    const int endm1 = end - 1;
    int   c0,  c1,  c2,  c3,  c4,  c5,  c6,  c7;
    int   c8,  c9,  c10, c11, c12, c13, c14, c15;
    float v0,  v1,  v2,  v3,  v4,  v5,  v6,  v7;
    float v8,  v9,  v10, v11, v12, v13, v14, v15;
#define EDGE_LD(i) { int idx = (e + i < end) ? e + i : endm1;                \
                     c##i = edge_col[idx];                                   \
                     v##i = (e + i < end) ? edge_val[idx] : 0.f; }
    EDGE_LD(0)  EDGE_LD(1)  EDGE_LD(2)  EDGE_LD(3)
    EDGE_LD(4)  EDGE_LD(5)  EDGE_LD(6)  EDGE_LD(7)
    EDGE_LD(8)  EDGE_LD(9)  EDGE_LD(10) EDGE_LD(11)
    EDGE_LD(12) EDGE_LD(13) EDGE_LD(14) EDGE_LD(15)
#undef EDGE_LD
#define GATHER(j, ca, cb)                                                    \
    uint2 s##j = *(const uint2*)(support +                                   \
        (size_t)(hi_half ? (cb) : (ca)) * 64 + l32 * 2);
    GATHER(0, c0,  c1)  GATHER(1, c2,  c3)
    GATHER(2, c4,  c5)  GATHER(3, c6,  c7)
    GATHER(4, c8,  c9)  GATHER(5, c10, c11)
    GATHER(6, c12, c13) GATHER(7, c14, c15)
#undef GATHER
#define ACCUM(j, va, vb) {                                                   \
    float val = hi_half ? (vb) : (va);                                       \
    acc.x += val * bf16_lo(s##j.x);                                          \
    acc.y += val * bf16_hi(s##j.x);                                          \
    acc.z += val * bf16_lo(s##j.y);                                          \
    acc.w += val * bf16_hi(s##j.y); }
    ACCUM(0, v0,  v1)  ACCUM(1, v2,  v3)
    ACCUM(2, v4,  v5)  ACCUM(3, v6,  v7)
    ACCUM(4, v8,  v9)  ACCUM(5, v10, v11)
    ACCUM(6, v12, v13) ACCUM(7, v14, v15)
#undef ACCUM
    e += 16;
  }

  // combine the two half-wave partial sums
  acc.x += __shfl_xor(acc.x, 32, 64);
  acc.y += __shfl_xor(acc.y, 32, 64);
  acc.z += __shfl_xor(acc.z, 32, 64);
  acc.w += __shfl_xor(acc.w, 32, 64);

  if (!hi_half) {
    float4 b = *(const float4*)(bias + l32 * 4);
    float4 o;
    o.x = acc.x + b.x; o.y = acc.y + b.y;
    o.z = acc.z + b.z; o.w = acc.w + b.w;
    *(float4*)(out + (size_t)wid * OUT_F + l32 * 4) = o;
  }
}

// ---------- launch ----------
extern "C" void kernel_launch(void* const* d_in, const int* in_sizes, int n_in,
                              void* d_out, int out_size, void* d_ws, size_t ws_size,
                              hipStream_t stream) {
  const float* x        = (const float*)d_in[0];
  const int*   edge_row = (const int*)  d_in[1];
  const int*   edge_col = (const int*)  d_in[2];
  const float* edge_val = (const float*)d_in[3];
  const float* weight   = (const float*)d_in[4];
  const float* bias     = (const float*)d_in[5];
  float* out = (float*)d_out;

  unsigned char* ws = (unsigned char*)d_ws;
  size_t support_bytes = (size_t)N_NODES * OUT_F * 2;            // 25.6 MB bf16
  unsigned int* support = (unsigned int*)ws;
  size_t rp_off = (support_bytes + 255) & ~(size_t)255;
  int* row_ptr = (int*)(ws + rp_off);
  size_t wt_off = (rp_off + (size_t)(N_NODES + 1) * 4 + 255) & ~(size_t)255;
  unsigned short* wt = (unsigned short*)(ws + wt_off);

  hipLaunchKernelGGL(rowptr_kernel, dim3((N_NODES + 1 + 255) / 256), dim3(256), 0, stream,
                     edge_row, row_ptr);
  hipLaunchKernelGGL(wconv_kernel, dim3(128), dim3(256), 0, stream,
                     weight, wt);
  hipLaunchKernelGGL(gemm_xw_mfma, dim3((N_NODES + 63) / 64), dim3(256), 0, stream,
                     x, wt, support);
  hipLaunchKernelGGL(spmm_kernel, dim3(N_NODES / 4), dim3(256), 0, stream,
                     support, row_ptr, edge_col, edge_val, bias, out);
}